// Round 4
// baseline (502.454 us; speedup 1.0000x reference)
//
#include <hip/hip_runtime.h>
#include <stdint.h>

#define S_LEN 2048
#define BATCH 8
#define EMB   1024
#define GAMMA 0.5f

typedef unsigned short ushort_t;
typedef __attribute__((ext_vector_type(8))) short  short8;
typedef __attribute__((ext_vector_type(8))) unsigned short ushort8;
typedef __attribute__((ext_vector_type(4))) float  floatx4;
typedef __attribute__((ext_vector_type(8))) int    int32x8;

__device__ __forceinline__ ushort_t f2bf(float f) {
  uint32_t x = __float_as_uint(f);
  x += 0x7fffu + ((x >> 16) & 1u);   // RNE
  return (ushort_t)(x >> 16);
}

// float -> OCP e4m3fn, RNE, saturating. Inputs here are ~N(0,0.25), no NaN/Inf.
__device__ __forceinline__ uint8_t f2e4m3(float f) {
  uint32_t u = __float_as_uint(f);
  uint32_t sign = (u >> 24) & 0x80u;
  uint32_t a = u & 0x7FFFFFFFu;
  uint32_t r;
  if (a >= 0x43E80000u) {            // |f| >= 464 -> 448
    r = 0x7Eu;
  } else if (a >= 0x3C800000u) {     // normal (|f| >= 2^-6)
    uint32_t t = a + 0x0007FFFFu + ((a >> 20) & 1u);
    r = ((t >> 20) - 960u) & 0x7Fu;
  } else {                           // subnormal: quantum 2^-9
    r = (uint32_t)__float2int_rn(__uint_as_float(a) * 512.f);
  }
  return (uint8_t)(sign | r);
}

__device__ __forceinline__ void gl_lds16(const ushort_t* g, ushort_t* l) {
  __builtin_amdgcn_global_load_lds(
      (const __attribute__((address_space(1))) unsigned int*)g,
      (__attribute__((address_space(3))) unsigned int*)l, 16, 0, 0);
}
__device__ __forceinline__ void gl_lds16b(const uint8_t* g, uint8_t* l) {
  __builtin_amdgcn_global_load_lds(
      (const __attribute__((address_space(1))) unsigned int*)g,
      (__attribute__((address_space(3))) unsigned int*)l, 16, 0, 0);
}

// NT bf16 GEMM core: C(128x128) += A(128xK) * B(128xK)^T, both K-contiguous.
// 256 thr = 4 waves, 64x64 per wave, 16x16x32 MFMA, BK=32.
// LDS rows are 64B = 4 x 16B chunks; chunk position c holds global chunk
// c ^ ((row>>1)&3)  -> frag-read bank pattern becomes 2-way (free).
__device__ __forceinline__ void gemm_core(
    const ushort_t* __restrict__ A, const ushort_t* __restrict__ B,
    int lda, int ldb, int K,
    ushort_t* As, ushort_t* Bs, floatx4 (&acc)[4][4])
{
  const int tid  = threadIdx.x;
  const int wave = tid >> 6, lane = tid & 63;
  const int wr = (wave >> 1) * 64, wc = (wave & 1) * 64;
  const int lr = lane & 15, quad = lane >> 4;
  const int srow = lane >> 2;                              // row in 16-row chunk
  const int scol = (((lane & 3) ^ ((lane >> 3) & 3)) * 8); // swizzled global chunk
  const int c0 = wave * 2;
  const int rsel = quad ^ ((lr >> 1) & 3);                 // frag-read chunk

  for (int k0 = 0; k0 < K; k0 += 32) {
#pragma unroll
    for (int cc = 0; cc < 2; ++cc) {
      const int c = c0 + cc;
      gl_lds16(A + (size_t)(c * 16 + srow) * lda + k0 + scol, As + c * 512);
      gl_lds16(B + (size_t)(c * 16 + srow) * ldb + k0 + scol, Bs + c * 512);
    }
    __syncthreads();
    short8 af[4], bfr[4];
#pragma unroll
    for (int i = 0; i < 4; ++i)
      af[i] = *(const short8*)(As + (wr + i * 16 + lr) * 32 + rsel * 8);
#pragma unroll
    for (int j = 0; j < 4; ++j)
      bfr[j] = *(const short8*)(Bs + (wc + j * 16 + lr) * 32 + rsel * 8);
#pragma unroll
    for (int i = 0; i < 4; ++i) {
#pragma unroll
      for (int j = 0; j < 4; ++j)
        acc[i][j] = __builtin_amdgcn_mfma_f32_16x16x32_bf16(af[i], bfr[j], acc[i][j], 0, 0, 0);
    }
    __syncthreads();
  }
}

// ---------- prep ----------
__global__ __launch_bounds__(256) void k_quant_x(const float* __restrict__ X,
                                                 ushort_t* __restrict__ Xb) {
  size_t i = ((size_t)blockIdx.x * 256 + threadIdx.x) * 4;
  float4 v = *(const float4*)(X + i);
  *(ushort4*)(Xb + i) = make_ushort4(f2bf(v.x), f2bf(v.y), f2bf(v.z), f2bf(v.w));
}

__global__ __launch_bounds__(256) void k_quant_w(
    const float* __restrict__ Wq, const float* __restrict__ Wk,
    const float* __restrict__ Wv, ushort_t* __restrict__ W) {
  size_t i = ((size_t)blockIdx.x * 256 + threadIdx.x) * 4;
  int row = (int)(i >> 10), col = (int)(i & 1023);
  int sel = row >> 10, sr = row & 1023;
  const float* src = sel == 0 ? Wq : (sel == 1 ? Wk : Wv);
  float4 v = *(const float4*)(src + (size_t)sr * 1024 + col);
  *(ushort4*)(W + i) = make_ushort4(f2bf(v.x), f2bf(v.y), f2bf(v.z), f2bf(v.w));
}

__global__ __launch_bounds__(256) void k_bias_zero(
    const float* __restrict__ bq, const float* __restrict__ bk,
    const float* __restrict__ bv, float* __restrict__ bias,
    float* __restrict__ q2, float* __restrict__ k2, float* __restrict__ rsum) {
  int i = blockIdx.x * 256 + threadIdx.x;
  if (i < 1024)       bias[i] = bq[i];
  else if (i < 2048)  bias[i] = bk[i - 1024];
  else if (i < 3072)  bias[i] = bv[i - 2048];
  if (i < BATCH * S_LEN) { q2[i] = 0.f; k2[i] = 0.f; rsum[i] = 0.f; }
}

// ---------- GEMM 1: QKV projection ----------
// Q,K -> fp8 e4m3 (x8 pre-scale) [b][t][e]; V -> bf16 TRANSPOSED Vt[b][e][j];
// q2/k2 = fp32 row sums of squares (of unquantized values).
__global__ __launch_bounds__(256) void k_gemm_qkv(
    const ushort_t* __restrict__ Xb, const ushort_t* __restrict__ W,
    const float* __restrict__ bias,
    uint8_t* __restrict__ Qf8, uint8_t* __restrict__ Kf8,
    ushort_t* __restrict__ Vt,
    float* __restrict__ q2, float* __restrict__ k2) {
  __shared__ ushort_t smem[8192];          // 16 KB: gemm As/Bs, then epilogue staging
  ushort_t* As = smem;
  ushort_t* Bs = smem + 4096;
  const int mt = blockIdx.x * 128, nt = blockIdx.y * 128;
  floatx4 acc[4][4];
  const floatx4 z = {0.f, 0.f, 0.f, 0.f};
#pragma unroll
  for (int i = 0; i < 4; ++i)
#pragma unroll
    for (int j = 0; j < 4; ++j) acc[i][j] = z;

  gemm_core(Xb + (size_t)mt * EMB, W + (size_t)nt * EMB, EMB, EMB, EMB, As, Bs, acc);
  // gemm_core ends with __syncthreads(): smem reusable.

  const int tid = threadIdx.x;
  const int lane = tid & 63, wave = tid >> 6;
  const int wr = (wave >> 1) * 64, wc = (wave & 1) * 64;
  const int lr = lane & 15, quad = lane >> 4;
  const int which = nt >> 10;        // 0=q 1=k 2=v
  const int nc0 = nt & 1023;
  float bv4[4];
#pragma unroll
  for (int j = 0; j < 4; ++j) bv4[j] = bias[nt + wc + j * 16 + lr];

  if (which < 2) {
    uint8_t* dst = which == 0 ? Qf8 : Kf8;
    float* sq = which == 0 ? q2 : k2;
    uint8_t* sT = (uint8_t*)smem;    // 128 x 128 fp8 tile = 16 KB
#pragma unroll
    for (int i = 0; i < 4; ++i) {
#pragma unroll
      for (int r = 0; r < 4; ++r) {
        const int row = wr + i * 16 + quad * 4 + r;
        const int g = mt + row, t = g >> 3, b = g & 7;
        float ss = 0.f;
#pragma unroll
        for (int j = 0; j < 4; ++j) {
          const float val = acc[i][j][r] + bv4[j];
          ss += val * val;
          sT[row * 128 + wc + j * 16 + lr] = f2e4m3(val * 8.f);
        }
        ss += __shfl_xor(ss, 1);
        ss += __shfl_xor(ss, 2);
        ss += __shfl_xor(ss, 4);
        ss += __shfl_xor(ss, 8);
        if (lr == 0) atomicAdd(&sq[b * S_LEN + t], ss);
      }
    }
    __syncthreads();
#pragma unroll
    for (int k4 = 0; k4 < 4; ++k4) {
      const int c = k4 * 256 + tid;
      const int row = c >> 3, off = (c & 7) * 16;
      const int b = row & 7, t = (mt + row) >> 3;
      *(uint4*)(dst + ((size_t)(b * S_LEN + t)) * EMB + nc0 + off) =
          *(const uint4*)(sT + row * 128 + off);
    }
  } else {
    // V: transpose through LDS in two 64-col passes (128x64 bf16 = 16 KB).
    const int t0 = mt >> 3;
#pragma unroll
    for (int p = 0; p < 2; ++p) {
      if ((wave & 1) == p) {
#pragma unroll
        for (int i = 0; i < 4; ++i)
#pragma unroll
          for (int r = 0; r < 4; ++r) {
            const int row = wr + i * 16 + quad * 4 + r;
#pragma unroll
            for (int j = 0; j < 4; ++j)
              smem[row * 64 + j * 16 + lr] = f2bf(acc[i][j][r] + bv4[j]);
          }
      }
      __syncthreads();
#pragma unroll
      for (int cc = 0; cc < 2; ++cc) {
        const int c = cc * 256 + tid;
        const int b = c >> 6, e = c & 63;
        ushort8 o0, o1;
#pragma unroll
        for (int m = 0; m < 8; ++m) {
          o0[m] = smem[(m * 8 + b) * 64 + e];
          o1[m] = smem[((m + 8) * 8 + b) * 64 + e];
        }
        const size_t base = ((size_t)(b * EMB + nc0 + p * 64 + e)) * S_LEN + t0;
        *(ushort8*)(Vt + base) = o0;
        *(ushort8*)(Vt + base + 8) = o1;
      }
      __syncthreads();
    }
  }
}

// ---------- GEMM 2: logits via MX-fp8 (unit scales) ----------
// acc = 64 * (q.k);  d2 = q2 + k2 - acc/32;  P = exp(-g*max(d2,0)) bf16.
__global__ __launch_bounds__(256) void k_logits(
    const uint8_t* __restrict__ Qf8, const uint8_t* __restrict__ Kf8,
    const float* __restrict__ q2, const float* __restrict__ k2,
    ushort_t* __restrict__ P, float* __restrict__ rsum) {
  __shared__ uint8_t sA[16384], sB[16384];   // 128 x 128B rows, xor-swizzled chunks
  const int b = blockIdx.z;
  const int mt = blockIdx.x * 128, nt = blockIdx.y * 128;
  const int tid = threadIdx.x, wave = tid >> 6, lane = tid & 63;
  const int wr = (wave >> 1) * 64, wc = (wave & 1) * 64;
  const int lr = lane & 15, quad = lane >> 4;
  const uint8_t* Ab = Qf8 + ((size_t)b * S_LEN + mt) * EMB;
  const uint8_t* Bb = Kf8 + ((size_t)b * S_LEN + nt) * EMB;

  floatx4 acc[4][4];
  const floatx4 z = {0.f, 0.f, 0.f, 0.f};
#pragma unroll
  for (int i = 0; i < 4; ++i)
#pragma unroll
    for (int j = 0; j < 4; ++j) acc[i][j] = z;

  const int srow8 = lane >> 3;                       // 0..7
  const int schunk = (lane & 7) ^ (srow8 & 7);       // swizzled global chunk

  union F8 { int32x8 v; int4 q[2]; };

  for (int k0 = 0; k0 < EMB; k0 += 128) {
#pragma unroll
    for (int i = 0; i < 4; ++i) {
      const int rbase = wave * 32 + i * 8;
      const int row = rbase + srow8;
      gl_lds16b(Ab + (size_t)row * EMB + k0 + schunk * 16, sA + rbase * 128);
      gl_lds16b(Bb + (size_t)row * EMB + k0 + schunk * 16, sB + rbase * 128);
    }
    __syncthreads();
    F8 af[4], bf[4];
#pragma unroll
    for (int i = 0; i < 4; ++i) {
      const int R = wr + i * 16 + lr, s = R & 7;
      af[i].q[0] = *(const int4*)(sA + R * 128 + (((2 * quad)     ^ s) * 16));
      af[i].q[1] = *(const int4*)(sA + R * 128 + (((2 * quad + 1) ^ s) * 16));
    }
#pragma unroll
    for (int j = 0; j < 4; ++j) {
      const int R = wc + j * 16 + lr, s = R & 7;
      bf[j].q[0] = *(const int4*)(sB + R * 128 + (((2 * quad)     ^ s) * 16));
      bf[j].q[1] = *(const int4*)(sB + R * 128 + (((2 * quad + 1) ^ s) * 16));
    }
#pragma unroll
    for (int i = 0; i < 4; ++i)
#pragma unroll
      for (int j = 0; j < 4; ++j)
        acc[i][j] = __builtin_amdgcn_mfma_scale_f32_16x16x128_f8f6f4(
            af[i].v, bf[j].v, acc[i][j], 0, 0, 0, 0x7F7F7F7F, 0, 0x7F7F7F7F);
    __syncthreads();
  }

  float k2v[4];
#pragma unroll
  for (int j = 0; j < 4; ++j) k2v[j] = k2[b * S_LEN + nt + wc + j * 16 + lr];

#pragma unroll
  for (int i = 0; i < 4; ++i) {
#pragma unroll
    for (int r = 0; r < 4; ++r) {
      const int t = mt + wr + i * 16 + quad * 4 + r;
      const float q2v = q2[b * S_LEN + t];
      float ss = 0.f;
#pragma unroll
      for (int j = 0; j < 4; ++j) {
        float d2 = q2v + k2v[j] - 0.03125f * acc[i][j][r];
        d2 = fmaxf(d2, 0.f);
        const float p = __expf(-GAMMA * d2);
        P[((size_t)b * S_LEN + t) * S_LEN + nt + wc + j * 16 + lr] = f2bf(p);
        ss += p;
      }
      ss += __shfl_xor(ss, 1);
      ss += __shfl_xor(ss, 2);
      ss += __shfl_xor(ss, 4);
      ss += __shfl_xor(ss, 8);
      if (lr == 0) atomicAdd(&rsum[b * S_LEN + t], ss);
    }
  }
}

// ---------- GEMM 3: O = (P @ V) / rowsum ----------
__global__ __launch_bounds__(256) void k_out(
    const ushort_t* __restrict__ P, const ushort_t* __restrict__ Vt,
    const float* __restrict__ rsum, float* __restrict__ out) {
  __shared__ ushort_t smem[8192];
  ushort_t* As = smem;
  ushort_t* Bs = smem + 4096;
  const int b = blockIdx.z;
  const int mt = blockIdx.x * 128, nt = blockIdx.y * 128;
  floatx4 acc[4][4];
  const floatx4 z = {0.f, 0.f, 0.f, 0.f};
#pragma unroll
  for (int i = 0; i < 4; ++i)
#pragma unroll
    for (int j = 0; j < 4; ++j) acc[i][j] = z;

  gemm_core(P + ((size_t)b * S_LEN + mt) * S_LEN,
            Vt + ((size_t)b * EMB + nt) * S_LEN, S_LEN, S_LEN, S_LEN, As, Bs, acc);

  const int lane = threadIdx.x & 63, wave = threadIdx.x >> 6;
  const int wr = (wave >> 1) * 64, wc = (wave & 1) * 64;
  const int lr = lane & 15, quad = lane >> 4;
#pragma unroll
  for (int i = 0; i < 4; ++i) {
#pragma unroll
    for (int r = 0; r < 4; ++r) {
      const int t = mt + wr + i * 16 + quad * 4 + r;
      const float rinv = 1.f / rsum[b * S_LEN + t];
#pragma unroll
      for (int j = 0; j < 4; ++j) {
        const int e = nt + wc + j * 16 + lr;
        out[((size_t)t * BATCH + b) * EMB + e] = acc[i][j][r] * rinv;
      }
    }
  }
}

extern "C" void kernel_launch(void* const* d_in, const int* in_sizes, int n_in,
                              void* d_out, int out_size, void* d_ws, size_t ws_size,
                              hipStream_t stream) {
  (void)in_sizes; (void)n_in; (void)out_size; (void)ws_size;
  const float* X  = (const float*)d_in[0];
  const float* Wq = (const float*)d_in[1];
  const float* bq = (const float*)d_in[2];
  const float* Wk = (const float*)d_in[3];
  const float* bk = (const float*)d_in[4];
  const float* Wv = (const float*)d_in[5];
  const float* bv = (const float*)d_in[6];
  float* out = (float*)d_out;
  char* ws = (char*)d_ws;

  // workspace layout (bytes); Xb aliases P (Xb dead before P is written)
  uint8_t*  Qf8  = (uint8_t*)(ws + 0);            // 16,777,216
  uint8_t*  Kf8  = (uint8_t*)(ws + 16777216);     // 16,777,216
  ushort_t* Vt   = (ushort_t*)(ws + 33554432);    // 33,554,432
  ushort_t* P    = (ushort_t*)(ws + 67108864);    // 67,108,864
  ushort_t* Xb   = (ushort_t*)(ws + 67108864);    // alias of P[0:33.5M]
  ushort_t* Wqkv = (ushort_t*)(ws + 134217728);   //  6,291,456
  float*    bias = (float*)(ws + 140509184);      //     12,288
  float*    q2   = (float*)(ws + 140521472);      //     65,536
  float*    k2   = (float*)(ws + 140587008);      //     65,536
  float*    rsum = (float*)(ws + 140652544);      //     65,536  -> ~134 MiB total

  k_quant_x <<<16384, 256, 0, stream>>>(X, Xb);
  k_quant_w <<<3072, 256, 0, stream>>>(Wq, Wk, Wv, Wqkv);
  k_bias_zero<<<64, 256, 0, stream>>>(bq, bk, bv, bias, q2, k2, rsum);
  k_gemm_qkv<<<dim3(128, 24), 256, 0, stream>>>(Xb, Wqkv, bias, Qf8, Kf8, Vt, q2, k2);
  k_logits  <<<dim3(16, 16, 8), 256, 0, stream>>>(Qf8, Kf8, q2, k2, P, rsum);
  k_out     <<<dim3(16, 8, 8), 256, 0, stream>>>(P, Vt, rsum, out);
}